// Round 9
// baseline (598.423 us; speedup 1.0000x reference)
//
#include <hip/hip_runtime.h>

#define BB 512
#define TT 256
#define PS 40   // PN row stride in halves (80B rows)

typedef __attribute__((ext_vector_type(2)))  _Float16 h2;
typedef __attribute__((ext_vector_type(4)))  _Float16 h4;
typedef __attribute__((ext_vector_type(8)))  _Float16 h8;
typedef __attribute__((ext_vector_type(4)))  unsigned u4v;
typedef __attribute__((ext_vector_type(16))) float f16v;
typedef __attribute__((ext_vector_type(4)))  float f4v;

#define MFMA(a,b,c) __builtin_amdgcn_mfma_f32_32x32x16_f16((a),(b),(c),0,0,0)

static __device__ __forceinline__ h2 pkh2(float x0, float x1) {
    return __builtin_bit_cast(h2, __builtin_amdgcn_cvt_pkrtz(x0, x1));
}
// pack-split: |x - (hi+lo)| <~ 2^-21 |x|
static __device__ __forceinline__ void pksplit(float x0, float x1, unsigned& hi, unsigned& lo) {
    h2 h = pkh2(x0, x1);
    h2 l = pkh2(x0 - (float)h[0], x1 - (float)h[1]);
    hi = __builtin_bit_cast(unsigned, h);
    lo = __builtin_bit_cast(unsigned, l);
}

// Build A/B-fragment (fp16 hi/lo) of a 32x32 matrix held in C-layout regs.
// C-layout: lane (c,h) reg r holds M[(r&3)+8(r>>2)+4h][c].
// Frag out: lane (c,h) kk holds M[16kk+8h+j][c]  (as B-frag = M; as A-frag = M^T).
static __device__ __forceinline__ void mkfrag(const f16v M, int h, h8 Ah[2], h8 Al[2]) {
    unsigned ph[8], pl[8], xh[8], xl[8];
    #pragma unroll
    for (int q = 0; q < 8; ++q) pksplit(M[2*q], M[2*q+1], ph[q], pl[q]);
    #pragma unroll
    for (int q = 0; q < 8; ++q) {
        xh[q] = (unsigned)__shfl_xor((int)ph[q], 32, 64);
        xl[q] = (unsigned)__shfl_xor((int)pl[q], 32, 64);
    }
    u4v a0h = { h ? xh[2] : ph[0], h ? xh[3] : ph[1], h ? ph[2] : xh[0], h ? ph[3] : xh[1] };
    u4v a1h = { h ? xh[6] : ph[4], h ? xh[7] : ph[5], h ? ph[6] : xh[4], h ? ph[7] : xh[5] };
    u4v a0l = { h ? xl[2] : pl[0], h ? xl[3] : pl[1], h ? pl[2] : xl[0], h ? pl[3] : xl[1] };
    u4v a1l = { h ? xl[6] : pl[4], h ? xl[7] : pl[5], h ? pl[6] : xl[4], h ? pl[7] : xl[5] };
    Ah[0] = __builtin_bit_cast(h8, a0h);  Ah[1] = __builtin_bit_cast(h8, a1h);
    Al[0] = __builtin_bit_cast(h8, a0l);  Al[1] = __builtin_bit_cast(h8, a1l);
}

static __device__ __forceinline__ h8 ld8h(const _Float16* p) {
    h4 a = *(const h4*)p;
    h4 b = *(const h4*)(p + 4);
    h8 r;
    r[0]=a[0]; r[1]=a[1]; r[2]=a[2]; r[3]=a[3];
    r[4]=b[0]; r[5]=b[1]; r[6]=b[2]; r[7]=b[3];
    return r;
}

// One chain per wave. Latency-flattened step:
//   T1 = P F^T ;  Z = F T1 + Q ;  W = (H T1)^T  (NO LDS on the gain path)
//   S = H (HP)^T + R  (LDS hop feeds only the tiny 4x4 S)
//   P' = Z - W Sinv W^T  folded into Z's three partial accumulators (depth 1).
// All hi/lo products use 3 INDEPENDENT accumulators of depth 2 (kk-halves).
__global__ __launch_bounds__(64, 1)
void kalman_v9(const float* __restrict__ obs,
               const float* __restrict__ Fg,
               const float* __restrict__ Qg,
               const float* __restrict__ Hg,
               const float* __restrict__ Rg,
               const float* __restrict__ im,
               const float* __restrict__ ic,
               float* __restrict__ out)
{
    __shared__ __align__(16) _Float16 sPN[4*PS];   // [n][k] = PHt[k][n] (hi only)
    __shared__ __align__(16) float sm[32];

    const int lane = threadIdx.x;
    const int b    = blockIdx.x;
    const int c    = lane & 31;
    const int h    = lane >> 5;

    // ---- constant fragments: F, H (fp16 hi/lo) ----
    h8 Fh[2], Fl[2], Hh[2], Hl[2];
    #pragma unroll
    for (int kk = 0; kk < 2; ++kk) {
        #pragma unroll
        for (int j = 0; j < 8; ++j) {
            int k = kk*16 + h*8 + j;
            float f = Fg[c*32 + k];
            _Float16 fh = (_Float16)f;
            Fh[kk][j] = fh;
            Fl[kk][j] = (_Float16)(f - (float)fh);
            float hv = (c < 4) ? Hg[c*32 + k] : 0.f;
            _Float16 hh = (_Float16)hv;
            Hh[kk][j] = hh;
            Hl[kk][j] = (_Float16)(hv - (float)hh);
        }
    }

    // ---- dot rows in registers: lanes<32 F[lane][:], lanes>=32 H[lane&3][:] ----
    float Frow[32];
    #pragma unroll
    for (int k = 0; k < 32; ++k)
        Frow[k] = (lane < 32) ? Fg[c*32 + k] : Hg[(lane & 3)*32 + k];

    // ---- Q and P in C-layout registers ----
    f16v Qc, P;
    #pragma unroll
    for (int reg = 0; reg < 16; ++reg) {
        int row = (reg & 3) + 8*(reg >> 2) + 4*h;
        Qc[reg] = Qg[row*32 + c];
        P[reg]  = ic[(size_t)b*1024 + row*32 + c];
    }
    float Rc[4] = {0.f, 0.f, 0.f, 0.f};
    if (c < 4) {
        #pragma unroll
        for (int m = 0; m < 4; ++m) Rc[m] = Rg[m*4 + c];
    }
    if (lane < 32) sm[lane] = im[b*32 + lane];

    const bool yl = (lane >= 32 && lane < 36);
    const float* obsp = obs + (size_t)b*TT*4 + (yl ? (lane - 32) : 0);
    float* om = out;
    float* oc = out + (size_t)TT * BB * 4;

    float yv = yl ? obsp[0] : 0.f;

    for (int t = 0; t < TT; ++t) {
        float yv_nxt = (yl && t + 1 < TT) ? obsp[(t + 1) * 4] : 0.f;

        // lanes<32: Fm[lane]; lanes>=32: mm[lane&3]
        float dotv = 0.f;
        #pragma unroll
        for (int q = 0; q < 8; ++q) {
            f4v mv = *(const f4v*)&sm[4*q];
            dotv += Frow[4*q+0]*mv.x + Frow[4*q+1]*mv.y
                  + Frow[4*q+2]*mv.z + Frow[4*q+3]*mv.w;
        }

        // ---- P fragment (symmetric: A == B frag) ----
        h8 Ph[2], Pl[2];
        mkfrag(P, h, Ph, Pl);

        // ---- HP = H*P  (2 indep accs, depth 2; P hi only — feeds S only) ----
        f16v hp1 = MFMA(Hh[0], Ph[0], (f16v)0.0f);
        f16v hp2 = MFMA(Hl[0], Ph[0], (f16v)0.0f);
        hp1 = MFMA(Hh[1], Ph[1], hp1);
        hp2 = MFMA(Hl[1], Ph[1], hp2);

        // ---- T1 = P*F^T  (3 indep accs, depth 2) ----
        f16v u1 = MFMA(Ph[0], Fh[0], (f16v)0.0f);
        f16v u2 = MFMA(Ph[0], Fl[0], (f16v)0.0f);
        f16v u3 = MFMA(Pl[0], Fh[0], (f16v)0.0f);
        u1 = MFMA(Ph[1], Fh[1], u1);
        u2 = MFMA(Ph[1], Fl[1], u2);
        u3 = MFMA(Pl[1], Fh[1], u3);

        // ---- resid + mean output (dotv ready; shfl-broadcast resid) ----
        float residv = yv - dotv;
        yv = yv_nxt;
        if (yl) om[((size_t)t*BB + b)*4 + (lane - 32)] = dotv;
        float r0 = __shfl(residv, 32, 64), r1 = __shfl(residv, 33, 64);
        float r2 = __shfl(residv, 34, 64), r3 = __shfl(residv, 35, 64);

        // ---- scatter PHt rows (hi only): sPN[n][k=c], lanes h==0 hold PHt[c][n] ----
        if (lane < 32) {
            h2 a01 = pkh2(hp1[0]+hp2[0], hp1[1]+hp2[1]);
            h2 a23 = pkh2(hp1[2]+hp2[2], hp1[3]+hp2[3]);
            sPN[0*PS + c] = a01[0];  sPN[1*PS + c] = a01[1];
            sPN[2*PS + c] = a23[0];  sPN[3*PS + c] = a23[1];
        }

        // ---- T1 combine + fragment ----
        f16v Tp = u1 + u2 + u3;
        h8 Th[2], Tl[2];
        mkfrag(Tp, h, Th, Tl);

        // ---- N frag (B of PHt, hi only), lanes c<4 ----
        h8 N0, N1;
        if (c < 4) {
            N0 = ld8h(&sPN[c*PS + 8*h]);
            N1 = ld8h(&sPN[c*PS + 16 + 8*h]);
        } else {
            N0 = (h8)(_Float16)0; N1 = (h8)(_Float16)0;
        }

        // ---- S = H*PHt + R  (2 indep accs, depth 2) ----
        f16v s1 = MFMA(Hh[0], N0, (f16v)0.0f);
        f16v s2 = MFMA(Hl[0], N0, (f16v)0.0f);
        s1 = MFMA(Hh[1], N1, s1);
        s2 = MFMA(Hl[1], N1, s2);

        // ---- Z = F*T1 + Q  and  W^T = H*T1  (6 indep accs, depth 2; issue together) ----
        f16v z1 = MFMA(Fh[0], Th[0], Qc);
        f16v z2 = MFMA(Fh[0], Tl[0], (f16v)0.0f);
        f16v z3 = MFMA(Fl[0], Th[0], (f16v)0.0f);
        f16v w1 = MFMA(Hh[0], Th[0], (f16v)0.0f);
        f16v w2 = MFMA(Hh[0], Tl[0], (f16v)0.0f);
        f16v w3 = MFMA(Hl[0], Th[0], (f16v)0.0f);
        z1 = MFMA(Fh[1], Th[1], z1);
        z2 = MFMA(Fh[1], Tl[1], z2);
        z3 = MFMA(Fl[1], Th[1], z3);
        w1 = MFMA(Hh[1], Th[1], w1);
        w2 = MFMA(Hh[1], Tl[1], w2);
        w3 = MFMA(Hl[1], Th[1], w3);

        // ---- S outputs + shfl broadcast (lane n holds S[m][n] in Smr[m]) ----
        float Smr[4];
        #pragma unroll
        for (int m = 0; m < 4; ++m) Smr[m] = s1[m] + s2[m] + Rc[m];
        if (lane < 4) {
            #pragma unroll
            for (int m = 0; m < 4; ++m)
                oc[(((size_t)t*BB + b)*4 + m)*4 + c] = Smr[m];
        }

        if (t == TT - 1) break;

        const float S0  = __shfl(Smr[0], 0, 64), S1  = __shfl(Smr[0], 1, 64),
                    S2  = __shfl(Smr[0], 2, 64), S3  = __shfl(Smr[0], 3, 64);
        const float S4  = __shfl(Smr[1], 0, 64), S5  = __shfl(Smr[1], 1, 64),
                    S6  = __shfl(Smr[1], 2, 64), S7  = __shfl(Smr[1], 3, 64);
        const float S8  = __shfl(Smr[2], 0, 64), S9  = __shfl(Smr[2], 1, 64),
                    S10 = __shfl(Smr[2], 2, 64), S11 = __shfl(Smr[2], 3, 64);
        const float S12 = __shfl(Smr[3], 0, 64), S13 = __shfl(Smr[3], 1, 64),
                    S14 = __shfl(Smr[3], 2, 64), S15 = __shfl(Smr[3], 3, 64);

        // ---- W rows (lane c holds W[c][0..3]; h==1 lanes auto-zero via H rows 4-7) ----
        const float W0 = w1[0] + w2[0] + w3[0];
        const float W1 = w1[1] + w2[1] + w3[1];
        const float W2 = w1[2] + w2[2] + w3[2];
        const float W3 = w1[3] + w2[3] + w3[3];

        // ---- Cramer inverse (fp32, redundant; overlaps Z/W MFMAs in flight) ----
        float nG0, nG1, nG2, nG3;
        {
            const float A2323 = S10*S15 - S11*S14;
            const float A1323 = S9 *S15 - S11*S13;
            const float A1223 = S9 *S14 - S10*S13;
            const float A0323 = S8 *S15 - S11*S12;
            const float A0223 = S8 *S14 - S10*S12;
            const float A0123 = S8 *S13 - S9 *S12;
            const float A2313 = S6 *S15 - S7 *S14;
            const float A1313 = S5 *S15 - S7 *S13;
            const float A1213 = S5 *S14 - S6 *S13;
            const float A2312 = S6 *S11 - S7 *S10;
            const float A1312 = S5 *S11 - S7 *S9;
            const float A1212 = S5 *S10 - S6 *S9;
            const float A0313 = S4 *S15 - S7 *S12;
            const float A0213 = S4 *S14 - S6 *S12;
            const float A0312 = S4 *S11 - S7 *S8;
            const float A0212 = S4 *S10 - S6 *S8;
            const float A0113 = S4 *S13 - S5 *S12;
            const float A0112 = S4 *S9  - S5 *S8;

            const float i00 =  (S5*A2323 - S6*A1323 + S7*A1223);
            const float i10 = -(S4*A2323 - S6*A0323 + S7*A0223);
            const float i20 =  (S4*A1323 - S5*A0323 + S7*A0123);
            const float i30 = -(S4*A1223 - S5*A0223 + S6*A0123);
            const float i01 = -(S1*A2323 - S2*A1323 + S3*A1223);
            const float i11 =  (S0*A2323 - S2*A0323 + S3*A0223);
            const float i21 = -(S0*A1323 - S1*A0323 + S3*A0123);
            const float i31 =  (S0*A1223 - S1*A0223 + S2*A0123);
            const float i02 =  (S1*A2313 - S2*A1313 + S3*A1213);
            const float i12 = -(S0*A2313 - S2*A0313 + S3*A0213);
            const float i22 =  (S0*A1313 - S1*A0313 + S3*A0113);
            const float i32 = -(S0*A1213 - S1*A0213 + S2*A0113);
            const float i03 = -(S1*A2312 - S2*A1312 + S3*A1212);
            const float i13 =  (S0*A2312 - S2*A0312 + S3*A0212);
            const float i23 = -(S0*A1312 - S1*A0312 + S3*A0112);
            const float i33 =  (S0*A1212 - S1*A0212 + S2*A0112);

            const float det = S0*i00 + S1*i10 + S2*i20 + S3*i30;
            const float nid = -1.0f / det;   // nG = -W*Sinv

            nG0 = nid * (W0*i00 + W1*i10 + W2*i20 + W3*i30);
            nG1 = nid * (W0*i01 + W1*i11 + W2*i21 + W3*i31);
            nG2 = nid * (W0*i02 + W1*i12 + W2*i22 + W3*i32);
            nG3 = nid * (W0*i03 + W1*i13 + W2*i23 + W3*i33);
        }

        // ---- mean update BEFORE correction (hides sm write->read) ----
        if (lane < 32)
            sm[lane] = dotv - (nG0*r0 + nG1*r1 + nG2*r2 + nG3*r3);

        // ---- pack G, W (h==1 lanes have W=0 -> G=0; upper k zeroed in-lane) ----
        h8 Gh8, Gl8, Wh8, Wl8;
        {
            unsigned g01, gl01, g23, gl23, w01, wl01, w23, wl23;
            pksplit(nG0, nG1, g01, gl01);
            pksplit(nG2, nG3, g23, gl23);
            pksplit(W0, W1, w01, wl01);
            pksplit(W2, W3, w23, wl23);
            u4v gh = {g01, g23, 0u, 0u}, gl = {gl01, gl23, 0u, 0u};
            u4v wh = {w01, w23, 0u, 0u}, wl = {wl01, wl23, 0u, 0u};
            Gh8 = __builtin_bit_cast(h8, gh);  Gl8 = __builtin_bit_cast(h8, gl);
            Wh8 = __builtin_bit_cast(h8, wh);  Wl8 = __builtin_bit_cast(h8, wl);
        }

        // ---- rank-4 correction folded into the z accumulators (depth 1) ----
        z1 = MFMA(Gh8, Wh8, z1);
        z2 = MFMA(Gh8, Wl8, z2);
        z3 = MFMA(Gl8, Wh8, z3);
        P = z1 + z2 + z3;
    }
}

extern "C" void kernel_launch(void* const* d_in, const int* in_sizes, int n_in,
                              void* d_out, int out_size, void* d_ws, size_t ws_size,
                              hipStream_t stream) {
    const float* obs       = (const float*)d_in[0];
    const float* F         = (const float*)d_in[1];
    const float* Q         = (const float*)d_in[2];
    const float* H         = (const float*)d_in[3];
    const float* R         = (const float*)d_in[4];
    const float* init_mean = (const float*)d_in[5];
    const float* init_cov  = (const float*)d_in[6];
    float* out = (float*)d_out;

    kalman_v9<<<BB, 64, 0, stream>>>(obs, F, Q, H, R, init_mean, init_cov, out);
}